// Round 5
// baseline (221.843 us; speedup 1.0000x reference)
//
#include <hip/hip_runtime.h>
#include <hip/hip_bf16.h>

// out[m,e] = sum_f relu( sum_q cos(x[m,q])cos(theta[q]) w1[f,q] ) * w2[e,f]
// M=16384, E=1024, F=4096. Pipeline:
//   1) w2cvt: w2 fp32 -> bf16 once into ws
//   2) qrelu: A = relu(qv @ w1^T) bf16 into ws
//   3) gemm8: out = A @ w2bf^T -- 256x256 tile, BK=64, 8 waves, 8-phase
//      schedule with READ-AHEAD-BY-ONE-PHASE (counted lgkmcnt keeps 4-12
//      ds_reads in flight under every MFMA cluster), gate-before-barrier
//      vmcnt, LDS XOR-swizzle, setprio, bijective XCD swizzle.

#define M_TOTAL 16384
#define E_DIM 1024
#define F_DIM 4096
#define NQ 8

typedef __attribute__((ext_vector_type(8))) short bf16x8;
typedef __attribute__((ext_vector_type(8))) unsigned short ushort8;
typedef __attribute__((ext_vector_type(4))) float f32x4;

__device__ __forceinline__ unsigned short f2bf(float f) {
  union { float f; unsigned u; } c; c.f = f;
  unsigned u = c.u + (0x7fffu + ((c.u >> 16) & 1u));
  return (unsigned short)(u >> 16);
}

// ---------------------------------------------------------------------------
__global__ __launch_bounds__(256) void w2cvt_kernel(
    const float* __restrict__ w2, unsigned short* __restrict__ w2bf) {
  size_t i = ((size_t)blockIdx.x * 256 + threadIdx.x) * 8;
  float v[8];
  *(float4*)&v[0] = *(const float4*)&w2[i];
  *(float4*)&v[4] = *(const float4*)&w2[i + 4];
  ushort8 p;
#pragma unroll
  for (int j = 0; j < 8; ++j) p[j] = f2bf(v[j]);
  *(ushort8*)&w2bf[i] = p;
}

// ---------------------------------------------------------------------------
__global__ __launch_bounds__(256) void qrelu_kernel(
    const float* __restrict__ x, const float* __restrict__ theta,
    const float* __restrict__ w1, unsigned short* __restrict__ A, int m_base) {
  __shared__ float qv[32][NQ];
  const int t = threadIdx.x;
  const int m0 = m_base + blockIdx.x * 32;
  {
    const int ml = t >> 3, q = t & 7;
    float xv = x[(size_t)(m0 + ml) * 1024 + q];
    qv[ml][q] = cosf(xv) * cosf(theta[q]);
  }
  __syncthreads();

  for (int oi = 0; oi < 2; ++oi) {
    const int o = t + oi * 256;  // f-octet index 0..511
    float w[64];
#pragma unroll
    for (int i = 0; i < 16; ++i)
      *(float4*)&w[i * 4] = *(const float4*)&w1[o * 64 + i * 4];
    for (int ml = 0; ml < 32; ++ml) {
      ushort8 pk;
#pragma unroll
      for (int j = 0; j < 8; ++j) {
        float s = 0.f;
#pragma unroll
        for (int q = 0; q < NQ; ++q) s = fmaf(qv[ml][q], w[j * 8 + q], s);
        pk[j] = f2bf(s > 0.f ? s : 0.f);
      }
      *(ushort8*)&A[(size_t)(m0 - m_base + ml) * F_DIM + o * 8] = pk;
    }
  }
}

// ---------------------------------------------------------------------------
// GEMM: BM=BN=256, BK=64, 512 thr = 8 waves (2m x 4n), wave tile 128x64.
// LDS: As/Bs [2 buf][2 half][128*64] bf16 = 128 KiB. Swizzle: (row, chunk c)
// stored at chunk c ^ (row&7) -- pre-swizzled global source, XOR'd ds_read.
// Per K-tile (4 phases, quadrants (0,0)(0,1)(1,1)(1,0)), reads ONE PHASE
// AHEAD of use:
//   P0: rd bhi(k)[4];           st Bh0(k+1); | lgkm(4)  | q00(afP,blo_k)
//   P1: rd ms1(k)->afQ[8];      st Bh1(k+1); | lgkm(8)  | q01(afP,bhi)
//   P2:                         st Ah0(k+2); | lgkm(0)  | q11(afQ,bhi)
//       then vmcnt(2) gate BEFORE closing barrier (B(k+1) landed, all waves)
//   P3: rd ms0/blo(k+1)[12];    st Ah1(k+2); | lgkm(12) | q10(afQ,blo_k)
// DS pipe has 4/8/0/12 reads in flight under the four MFMA windows.
// ---------------------------------------------------------------------------
#define BAR __builtin_amdgcn_s_barrier()
#define SB __builtin_amdgcn_sched_barrier(0)
#define VM(n) asm volatile("s_waitcnt vmcnt(" #n ")" ::: "memory")

#define PHASE(AF, BF, ms, ns, W) do { \
  BAR; \
  asm volatile("s_waitcnt lgkmcnt(" #W ")" ::: "memory"); \
  __builtin_amdgcn_sched_barrier(0); \
  __builtin_amdgcn_s_setprio(1); \
  _Pragma("unroll") \
  for (int mt2 = 0; mt2 < 4; ++mt2) { \
    _Pragma("unroll") \
    for (int nt2 = 0; nt2 < 2; ++nt2) { \
      _Pragma("unroll") \
      for (int kk = 0; kk < 2; ++kk) { \
        acc[(ms) * 4 + mt2][(ns) * 2 + nt2] = \
            __builtin_amdgcn_mfma_f32_16x16x32_bf16( \
                AF[mt2][kk], BF[nt2][kk], acc[(ms) * 4 + mt2][(ns) * 2 + nt2], \
                0, 0, 0); \
      } } } \
  __builtin_amdgcn_s_setprio(0); \
  __builtin_amdgcn_sched_barrier(0); \
} while (0)

#define RD_A(buf, ms, AF) do { \
  _Pragma("unroll") \
  for (int mt2 = 0; mt2 < 4; ++mt2) { \
    AF[mt2][0] = *(const bf16x8*)&asW[(buf) * 16384 + (ms) * 4096 + mt2 * 1024 + aO0]; \
    AF[mt2][1] = *(const bf16x8*)&asW[(buf) * 16384 + (ms) * 4096 + mt2 * 1024 + aO1]; \
  } } while (0)

#define RD_B(buf, ns, BF) do { \
  _Pragma("unroll") \
  for (int nt2 = 0; nt2 < 2; ++nt2) { \
    BF[nt2][0] = *(const bf16x8*)&bsW[(buf) * 16384 + (ns) * 2048 + nt2 * 1024 + bO0]; \
    BF[nt2][1] = *(const bf16x8*)&bsW[(buf) * 16384 + (ns) * 2048 + nt2 * 1024 + bO1]; \
  } } while (0)

__global__ __launch_bounds__(512, 2) void gemm8_kernel(
    const unsigned short* __restrict__ Abf, const unsigned short* __restrict__ w2bf,
    float* __restrict__ out, int m_base) {
  __shared__ __align__(16) unsigned short As[2][2][128 * 64];
  __shared__ __align__(16) unsigned short Bs[2][2][128 * 64];

  const int tid = threadIdx.x;
  const int lane = tid & 63;
  const int wid = tid >> 6;
  const int wr = wid >> 2;  // m-half of block
  const int wc = wid & 3;   // n-quarter of block

  // T1: bijective XCD-chunked swizzle (m204); nb fastest within chunk so the
  // 4 blocks sharing an A-panel land on the same XCD (A L2-resident).
  const int nwg = gridDim.x;
  const int bid = blockIdx.x;
  const int qq = nwg >> 3, rr = nwg & 7;
  const int xcd = bid & 7, sub = bid >> 3;
  const int wgid =
      (xcd < rr ? xcd * (qq + 1) : rr * (qq + 1) + (xcd - rr) * qq) + sub;
  const int mb = wgid >> 2;
  const int nb = wgid & 3;

  const unsigned short* Ag = Abf + (size_t)mb * 256 * F_DIM;
  const unsigned short* Bg = w2bf + (size_t)nb * 256 * F_DIM;

  f32x4 acc[8][4] = {};
  bf16x8 afP[4][2], afQ[4][2], bloP[2][2], bloQ[2][2], bhi[2][2];

  // --- LDS read bases (fold to ds_read offset immediates) ---
  const int hi4 = lane >> 4, l7 = lane & 7, l15 = lane & 15;
  const int aO0 = l15 * 64 + ((hi4 ^ l7) << 3);
  const int aO1 = aO0 ^ 32;  // kk=1: chunk XOR 4
  const int bO0 = ((wc & 1) * 64 + l15) * 64 + ((hi4 ^ l7) << 3);
  const int bO1 = bO0 ^ 32;
  const unsigned short* asW = &As[0][wr][0];
  const unsigned short* bsW = &Bs[0][wc >> 1][0];

  // --- persistent global stage pointers (advance +64 elems per use) ---
  const int srow = tid >> 3;              // 0..63
  const int sc = (tid & 7) ^ (srow & 7);  // source-side swizzle
  const unsigned short* pA0 = Ag + (size_t)(srow)*F_DIM + sc * 8;
  const unsigned short* pA1 = Ag + (size_t)(64 + srow) * F_DIM + sc * 8;
  const unsigned short* pA2 = Ag + (size_t)(128 + srow) * F_DIM + sc * 8;
  const unsigned short* pA3 = Ag + (size_t)(192 + srow) * F_DIM + sc * 8;
  const unsigned short* pB0 = Bg + (size_t)(srow)*F_DIM + sc * 8;
  const unsigned short* pB1 = Bg + (size_t)(64 + srow) * F_DIM + sc * 8;
  const unsigned short* pB2 = Bg + (size_t)(128 + srow) * F_DIM + sc * 8;
  const unsigned short* pB3 = Bg + (size_t)(192 + srow) * F_DIM + sc * 8;

  auto stA = [&](int buf, int half, const unsigned short*& r0,
                 const unsigned short*& r1) {
    unsigned short* d = &As[buf][half][wid * 512];
    __builtin_amdgcn_global_load_lds(
        (const __attribute__((address_space(1))) void*)r0,
        (__attribute__((address_space(3))) void*)d, 16, 0, 0);
    __builtin_amdgcn_global_load_lds(
        (const __attribute__((address_space(1))) void*)r1,
        (__attribute__((address_space(3))) void*)(d + 4096), 16, 0, 0);
    r0 += 64; r1 += 64;
  };
  auto stB = [&](int buf, int half, const unsigned short*& r0,
                 const unsigned short*& r1) {
    unsigned short* d = &Bs[buf][half][wid * 512];
    __builtin_amdgcn_global_load_lds(
        (const __attribute__((address_space(1))) void*)r0,
        (__attribute__((address_space(3))) void*)d, 16, 0, 0);
    __builtin_amdgcn_global_load_lds(
        (const __attribute__((address_space(1))) void*)r1,
        (__attribute__((address_space(3))) void*)(d + 4096), 16, 0, 0);
    r0 += 64; r1 += 64;
  };

  // --- prologue: stage A(0),B(0),A(1); gate; pre-read ms0(0)+blo(0) ---
  stB(0, 0, pB0, pB1); stB(0, 1, pB2, pB3);
  stA(0, 0, pA0, pA1); stA(0, 1, pA2, pA3);
  stA(1, 0, pA0, pA1); stA(1, 1, pA2, pA3);
  VM(4);               // A(1)'s 4 loads may remain in flight
  BAR;                 // all waves' A(0)/B(0) landed
  RD_A(0, 0, afP); RD_B(0, 0, bloP);

#pragma unroll 1
  for (int it = 0; it < 32; ++it) {
    const bool s2 = (it < 31);
    // ======== even tile k=2it (buf0) ========
    // P0
    RD_B(0, 1, bhi);
    stB(1, 0, pB0, pB1);
    PHASE(afP, bloP, 0, 0, 4);  BAR;
    // P1
    RD_A(0, 1, afQ);
    stB(1, 1, pB2, pB3);
    PHASE(afP, bhi, 0, 1, 8);   BAR;
    // P2 (+ gate-before-barrier for buf1 reads at P3)
    if (s2) stA(0, 0, pA0, pA1);
    PHASE(afQ, bhi, 1, 1, 0);
    if (s2) { VM(2); } else { VM(0); }
    BAR;
    // P3: read tile k+1 one phase ahead; q10 runs on old regs
    RD_A(1, 0, afP); RD_B(1, 0, bloQ);
    if (s2) stA(0, 1, pA2, pA3);
    PHASE(afQ, bloP, 1, 0, 12); BAR;

    // ======== odd tile k=2it+1 (buf1) ========
    // P0
    RD_B(1, 1, bhi);
    if (s2) stB(0, 0, pB0, pB1);
    PHASE(afP, bloQ, 0, 0, 4);  BAR;
    // P1
    RD_A(1, 1, afQ);
    if (s2) stB(0, 1, pB2, pB3);
    PHASE(afP, bhi, 0, 1, 8);   BAR;
    // P2
    if (s2) stA(1, 0, pA0, pA1);
    PHASE(afQ, bhi, 1, 1, 0);
    if (s2) VM(2);
    BAR;
    // P3
    if (s2) {
      RD_A(0, 0, afP); RD_B(0, 0, bloP);
      stA(1, 1, pA2, pA3);
    }
    PHASE(afQ, bloQ, 1, 0, 12); BAR;
  }

  // Epilogue: C/D layout col = lane&15, row = (lane>>4)*4 + r [m89-verified]
  const int cl = lane & 15, rg = lane >> 4;
  float* ob = out + (size_t)(m_base + mb * 256 + wr * 128) * E_DIM + nb * 256 +
              wc * 64 + cl;
#pragma unroll
  for (int mt = 0; mt < 8; ++mt)
#pragma unroll
    for (int r = 0; r < 4; ++r) {
      float* orow = ob + (size_t)(mt * 16 + rg * 4 + r) * E_DIM;
#pragma unroll
      for (int nt = 0; nt < 4; ++nt) orow[nt * 16] = acc[mt][nt][r];
    }
}

// ---------------------------------------------------------------------------
extern "C" void kernel_launch(void* const* d_in, const int* in_sizes, int n_in,
                              void* d_out, int out_size, void* d_ws, size_t ws_size,
                              hipStream_t stream) {
  const float* x = (const float*)d_in[0];
  const float* theta = (const float*)d_in[1];
  const float* w1 = (const float*)d_in[2];
  const float* w2 = (const float*)d_in[3];
  float* out = (float*)d_out;

  unsigned short* w2bf = (unsigned short*)d_ws;           // 8 MiB
  unsigned short* A = w2bf + (size_t)E_DIM * F_DIM;       // rest of ws

  size_t abytes = ws_size - (size_t)E_DIM * F_DIM * 2;
  size_t maxrows = abytes / ((size_t)F_DIM * 2);
  int Mc = (int)((maxrows / 256) * 256);
  if (Mc > M_TOTAL) Mc = M_TOTAL;
  if (Mc < 256) Mc = 256;

  w2cvt_kernel<<<E_DIM * F_DIM / 2048, 256, 0, stream>>>(w2, w2bf);

  for (int mb = 0; mb < M_TOTAL; mb += Mc) {
    int rows = M_TOTAL - mb < Mc ? M_TOTAL - mb : Mc;
    qrelu_kernel<<<rows / 32, 256, 0, stream>>>(x, theta, w1, A, mb);
    gemm8_kernel<<<(rows / 256) * 4, 512, 0, stream>>>(A, w2bf, out, mb);
  }
}

// Round 6
// 196.087 us; speedup vs baseline: 1.1313x; 1.1313x over previous
//
#include <hip/hip_runtime.h>
#include <hip/hip_bf16.h>

// out[m,e] = sum_f relu( sum_q cos(x[m,q])cos(theta[q]) w1[f,q] ) * w2[e,f]
// M=16384, E=1024, F=4096. Pipeline:
//   1) w2cvt: w2 fp32 -> bf16 once into ws
//   2) qrelu: A = relu(qv @ w1^T) bf16 into ws
//   3) gemm: out = A @ w2bf^T -- 256x256 tile, BK=64, 8 waves (2m x 4n),
//      ONE region per K-tile: stage(kt+1) + 24 ds_reads + 64 MFMA, all
//      compiler-scheduled (counted lgkm interleave), single barrier/K-tile,
//      vmcnt(0) gate before barrier. LDS XOR-swizzle, XCD swizzle.

#define M_TOTAL 16384
#define E_DIM 1024
#define F_DIM 4096
#define NQ 8

typedef __attribute__((ext_vector_type(8))) short bf16x8;
typedef __attribute__((ext_vector_type(8))) unsigned short ushort8;
typedef __attribute__((ext_vector_type(4))) float f32x4;

__device__ __forceinline__ unsigned short f2bf(float f) {
  union { float f; unsigned u; } c; c.f = f;
  unsigned u = c.u + (0x7fffu + ((c.u >> 16) & 1u));
  return (unsigned short)(u >> 16);
}

// ---------------------------------------------------------------------------
__global__ __launch_bounds__(256) void w2cvt_kernel(
    const float* __restrict__ w2, unsigned short* __restrict__ w2bf) {
  size_t i = ((size_t)blockIdx.x * 256 + threadIdx.x) * 8;
  float v[8];
  *(float4*)&v[0] = *(const float4*)&w2[i];
  *(float4*)&v[4] = *(const float4*)&w2[i + 4];
  ushort8 p;
#pragma unroll
  for (int j = 0; j < 8; ++j) p[j] = f2bf(v[j]);
  *(ushort8*)&w2bf[i] = p;
}

// ---------------------------------------------------------------------------
__global__ __launch_bounds__(256) void qrelu_kernel(
    const float* __restrict__ x, const float* __restrict__ theta,
    const float* __restrict__ w1, unsigned short* __restrict__ A, int m_base) {
  __shared__ float qv[32][NQ];
  const int t = threadIdx.x;
  const int m0 = m_base + blockIdx.x * 32;
  {
    const int ml = t >> 3, q = t & 7;
    float xv = x[(size_t)(m0 + ml) * 1024 + q];
    qv[ml][q] = cosf(xv) * cosf(theta[q]);
  }
  __syncthreads();

  for (int oi = 0; oi < 2; ++oi) {
    const int o = t + oi * 256;  // f-octet index 0..511
    float w[64];
#pragma unroll
    for (int i = 0; i < 16; ++i)
      *(float4*)&w[i * 4] = *(const float4*)&w1[o * 64 + i * 4];
    for (int ml = 0; ml < 32; ++ml) {
      ushort8 pk;
#pragma unroll
      for (int j = 0; j < 8; ++j) {
        float s = 0.f;
#pragma unroll
        for (int q = 0; q < NQ; ++q) s = fmaf(qv[ml][q], w[j * 8 + q], s);
        pk[j] = f2bf(s > 0.f ? s : 0.f);
      }
      *(ushort8*)&A[(size_t)(m0 - m_base + ml) * F_DIM + o * 8] = pk;
    }
  }
}

// ---------------------------------------------------------------------------
// GEMM: BM=BN=256, BK=64, 512 thr = 8 waves (2m x 4n), wave tile 128x64.
// LDS: As/Bs [2 buf][2 half][128*64] bf16 = 128 KiB. Swizzle: (row, chunk c)
// stored at chunk c ^ (row&7); pre-swizzled global source, XOR'd ds_read.
// One region per K-tile kt (buf = kt&1):
//   [stage kt+1 -> buf^1]  (8 global_load_lds; old contents of buf^1 were
//                           fully consumed last region -- reads complete
//                           before their consuming MFMAs, before the barrier)
//   [24 ds_read_b128 of buf + 64 MFMA]  -- NO pins; compiler emits counted
//                           lgkmcnt so the DS queue drains UNDER the MFMAs
//   [vmcnt(0)] [s_barrier]  -- RAW gate for buf^1 reads next region
// ---------------------------------------------------------------------------
#define BAR __builtin_amdgcn_s_barrier()
#define VM0 asm volatile("s_waitcnt vmcnt(0)" ::: "memory")

#define GLDS(src, dst) \
  __builtin_amdgcn_global_load_lds( \
      (const __attribute__((address_space(1))) void*)(src), \
      (__attribute__((address_space(3))) void*)(dst), 16, 0, 0)

#define STAGE_ALL(buf) do { \
  GLDS(pA0, &As[buf][0][wid * 512]); \
  GLDS(pA1, &As[buf][0][4096 + wid * 512]); \
  GLDS(pA2, &As[buf][1][wid * 512]); \
  GLDS(pA3, &As[buf][1][4096 + wid * 512]); \
  GLDS(pB0, &Bs[buf][0][wid * 512]); \
  GLDS(pB1, &Bs[buf][0][4096 + wid * 512]); \
  GLDS(pB2, &Bs[buf][1][wid * 512]); \
  GLDS(pB3, &Bs[buf][1][4096 + wid * 512]); \
  pA0 += 64; pA1 += 64; pA2 += 64; pA3 += 64; \
  pB0 += 64; pB1 += 64; pB2 += 64; pB3 += 64; \
} while (0)

#define COMPUTE(buf) do { \
  bf16x8 af[8][2], bfr[4][2]; \
  _Pragma("unroll") \
  for (int mt = 0; mt < 8; ++mt) { \
    af[mt][0] = *(const bf16x8*)&asW[(buf) * 16384 + mt * 1024 + aO0]; \
    af[mt][1] = *(const bf16x8*)&asW[(buf) * 16384 + mt * 1024 + aO1]; \
  } \
  _Pragma("unroll") \
  for (int nt = 0; nt < 4; ++nt) { \
    bfr[nt][0] = *(const bf16x8*)&bsW[(buf) * 16384 + nt * 1024 + bO0]; \
    bfr[nt][1] = *(const bf16x8*)&bsW[(buf) * 16384 + nt * 1024 + bO1]; \
  } \
  __builtin_amdgcn_s_setprio(1); \
  _Pragma("unroll") \
  for (int mt = 0; mt < 8; ++mt) \
    _Pragma("unroll") \
    for (int nt = 0; nt < 4; ++nt) \
      _Pragma("unroll") \
      for (int kk = 0; kk < 2; ++kk) \
        acc[mt][nt] = __builtin_amdgcn_mfma_f32_16x16x32_bf16( \
            af[mt][kk], bfr[nt][kk], acc[mt][nt], 0, 0, 0); \
  __builtin_amdgcn_s_setprio(0); \
} while (0)

__global__ __launch_bounds__(512, 2) void gemm_kernel(
    const unsigned short* __restrict__ Abf, const unsigned short* __restrict__ w2bf,
    float* __restrict__ out, int m_base) {
  __shared__ __align__(16) unsigned short As[2][2][128 * 64];
  __shared__ __align__(16) unsigned short Bs[2][2][128 * 64];

  const int tid = threadIdx.x;
  const int lane = tid & 63;
  const int wid = tid >> 6;
  const int wr = wid >> 2;  // m-half of block
  const int wc = wid & 3;   // n-quarter of block

  // T1: bijective XCD-chunked swizzle (m204); nb fastest within chunk so the
  // 4 blocks sharing an A-panel land on the same XCD (A L2-resident).
  const int nwg = gridDim.x;
  const int bid = blockIdx.x;
  const int qq = nwg >> 3, rr = nwg & 7;
  const int xcd = bid & 7, sub = bid >> 3;
  const int wgid =
      (xcd < rr ? xcd * (qq + 1) : rr * (qq + 1) + (xcd - rr) * qq) + sub;
  const int mb = wgid >> 2;
  const int nb = wgid & 3;

  const unsigned short* Ag = Abf + (size_t)mb * 256 * F_DIM;
  const unsigned short* Bg = w2bf + (size_t)nb * 256 * F_DIM;

  f32x4 acc[8][4] = {};

  // --- LDS read bases (fold to ds_read offset immediates) ---
  const int hi4 = lane >> 4, l7 = lane & 7, l15 = lane & 15;
  const int aO0 = l15 * 64 + ((hi4 ^ l7) << 3);
  const int aO1 = aO0 ^ 32;  // kk=1: chunk XOR 4
  const int bO0 = ((wc & 1) * 64 + l15) * 64 + ((hi4 ^ l7) << 3);
  const int bO1 = bO0 ^ 32;
  const unsigned short* asW = &As[0][wr][0];
  const unsigned short* bsW = &Bs[0][wc >> 1][0];

  // --- persistent global stage pointers (advance +64 elems per K-tile) ---
  const int srow = tid >> 3;              // 0..63
  const int sc = (tid & 7) ^ (srow & 7);  // source-side swizzle
  const unsigned short* pA0 = Ag + (size_t)(srow)*F_DIM + sc * 8;
  const unsigned short* pA1 = Ag + (size_t)(64 + srow) * F_DIM + sc * 8;
  const unsigned short* pA2 = Ag + (size_t)(128 + srow) * F_DIM + sc * 8;
  const unsigned short* pA3 = Ag + (size_t)(192 + srow) * F_DIM + sc * 8;
  const unsigned short* pB0 = Bg + (size_t)(srow)*F_DIM + sc * 8;
  const unsigned short* pB1 = Bg + (size_t)(64 + srow) * F_DIM + sc * 8;
  const unsigned short* pB2 = Bg + (size_t)(128 + srow) * F_DIM + sc * 8;
  const unsigned short* pB3 = Bg + (size_t)(192 + srow) * F_DIM + sc * 8;

  // --- prologue: stage kt0 -> buf0 ---
  STAGE_ALL(0);
  VM0;
  BAR;

#pragma unroll 1
  for (int t2 = 0; t2 < 32; ++t2) {
    // ---- region even: kt = 2*t2 (buf0); stage kt+1 -> buf1 ----
    STAGE_ALL(1);
    COMPUTE(0);
    VM0;
    BAR;
    // ---- region odd: kt = 2*t2+1 (buf1); stage kt+2 -> buf0 ----
    if (t2 < 31) STAGE_ALL(0);
    COMPUTE(1);
    VM0;
    BAR;
  }

  // Epilogue: C/D layout col = lane&15, row = (lane>>4)*4 + r [m89-verified]
  const int cl = lane & 15, rg = lane >> 4;
  float* ob = out + (size_t)(m_base + mb * 256 + wr * 128) * E_DIM + nb * 256 +
              wc * 64 + cl;
#pragma unroll
  for (int mt = 0; mt < 8; ++mt)
#pragma unroll
    for (int r = 0; r < 4; ++r) {
      float* orow = ob + (size_t)(mt * 16 + rg * 4 + r) * E_DIM;
#pragma unroll
      for (int nt = 0; nt < 4; ++nt) orow[nt * 16] = acc[mt][nt][r];
    }
}

// ---------------------------------------------------------------------------
extern "C" void kernel_launch(void* const* d_in, const int* in_sizes, int n_in,
                              void* d_out, int out_size, void* d_ws, size_t ws_size,
                              hipStream_t stream) {
  const float* x = (const float*)d_in[0];
  const float* theta = (const float*)d_in[1];
  const float* w1 = (const float*)d_in[2];
  const float* w2 = (const float*)d_in[3];
  float* out = (float*)d_out;

  unsigned short* w2bf = (unsigned short*)d_ws;           // 8 MiB
  unsigned short* A = w2bf + (size_t)E_DIM * F_DIM;       // rest of ws

  size_t abytes = ws_size - (size_t)E_DIM * F_DIM * 2;
  size_t maxrows = abytes / ((size_t)F_DIM * 2);
  int Mc = (int)((maxrows / 256) * 256);
  if (Mc > M_TOTAL) Mc = M_TOTAL;
  if (Mc < 256) Mc = 256;

  w2cvt_kernel<<<E_DIM * F_DIM / 2048, 256, 0, stream>>>(w2, w2bf);

  for (int mb = 0; mb < M_TOTAL; mb += Mc) {
    int rows = M_TOTAL - mb < Mc ? M_TOTAL - mb : Mc;
    qrelu_kernel<<<rows / 32, 256, 0, stream>>>(x, theta, w1, A, mb);
    gemm_kernel<<<(rows / 256) * 4, 512, 0, stream>>>(A, w2bf, out, mb);
  }
}

// Round 7
// 156.677 us; speedup vs baseline: 1.4159x; 1.2515x over previous
//
#include <hip/hip_runtime.h>
#include <hip/hip_bf16.h>

// out[m,e] = sum_f relu( sum_q cos(x[m,q])cos(theta[q]) w1[f,q] ) * w2[e,f]
// M=16384, E=1024, F=4096. Pipeline:
//   1) w2cvt: w2 fp32 -> bf16 once into ws
//   2) qrelu: A = relu(qv @ w1^T) bf16 into ws
//   3) gemm: out = A @ w2bf^T -- 256x256 tile, BK=64, 8 waves (2m x 4n).
//      ONE region per K-tile, no intra-tile barriers (waves self-stagger ->
//      DS pipe drains under other waves' MFMA clusters), quadrant-ordered
//      reads to cap frag liveness at ~64 VGPR (no spill), vmcnt(0) gate
//      before the single barrier. LDS XOR-swizzle, XCD swizzle, setprio.

#define M_TOTAL 16384
#define E_DIM 1024
#define F_DIM 4096
#define NQ 8

typedef __attribute__((ext_vector_type(8))) short bf16x8;
typedef __attribute__((ext_vector_type(8))) unsigned short ushort8;
typedef __attribute__((ext_vector_type(4))) float f32x4;

__device__ __forceinline__ unsigned short f2bf(float f) {
  union { float f; unsigned u; } c; c.f = f;
  unsigned u = c.u + (0x7fffu + ((c.u >> 16) & 1u));
  return (unsigned short)(u >> 16);
}

// ---------------------------------------------------------------------------
__global__ __launch_bounds__(256) void w2cvt_kernel(
    const float* __restrict__ w2, unsigned short* __restrict__ w2bf) {
  size_t i = ((size_t)blockIdx.x * 256 + threadIdx.x) * 8;
  float v[8];
  *(float4*)&v[0] = *(const float4*)&w2[i];
  *(float4*)&v[4] = *(const float4*)&w2[i + 4];
  ushort8 p;
#pragma unroll
  for (int j = 0; j < 8; ++j) p[j] = f2bf(v[j]);
  *(ushort8*)&w2bf[i] = p;
}

// ---------------------------------------------------------------------------
__global__ __launch_bounds__(256) void qrelu_kernel(
    const float* __restrict__ x, const float* __restrict__ theta,
    const float* __restrict__ w1, unsigned short* __restrict__ A, int m_base) {
  __shared__ float qv[32][NQ];
  const int t = threadIdx.x;
  const int m0 = m_base + blockIdx.x * 32;
  {
    const int ml = t >> 3, q = t & 7;
    float xv = x[(size_t)(m0 + ml) * 1024 + q];
    qv[ml][q] = cosf(xv) * cosf(theta[q]);
  }
  __syncthreads();

  for (int oi = 0; oi < 2; ++oi) {
    const int o = t + oi * 256;  // f-octet index 0..511
    float w[64];
#pragma unroll
    for (int i = 0; i < 16; ++i)
      *(float4*)&w[i * 4] = *(const float4*)&w1[o * 64 + i * 4];
    for (int ml = 0; ml < 32; ++ml) {
      ushort8 pk;
#pragma unroll
      for (int j = 0; j < 8; ++j) {
        float s = 0.f;
#pragma unroll
        for (int q = 0; q < NQ; ++q) s = fmaf(qv[ml][q], w[j * 8 + q], s);
        pk[j] = f2bf(s > 0.f ? s : 0.f);
      }
      *(ushort8*)&A[(size_t)(m0 - m_base + ml) * F_DIM + o * 8] = pk;
    }
  }
}

// ---------------------------------------------------------------------------
// GEMM: BM=BN=256, BK=64, 512 thr = 8 waves (2m x 4n), wave tile 128x64.
// LDS: As/Bs [2 buf][2 half][128*64] bf16 = 128 KiB. Swizzle: (row, chunk c)
// stored at chunk c ^ (row&7); pre-swizzled global source, XOR'd ds_read.
// Region(kt), buf = kt&1:
//   [stage kt+1 -> buf^1]                        8 global_load_lds
//   [rd af(mt0-3), blo, bhi : 16 ds_read]        liveness 64 VGPR
//   [q00 + q01 : 32 MFMA, setprio]               compiler-counted lgkm waits
//   sched_barrier(0)                             (no af2 hoist -> no spill)
//   [rd af(mt4-7) : 8 ds_read]
//   [q11 + q10 : 32 MFMA, setprio]
//   [vmcnt(0)] [s_barrier]                       RAW gate for buf^1
// WAR safety: every ds_read is consumed by an MFMA before the barrier, so
// the compiler's RAW waits imply read-completion before any wave crosses.
// ---------------------------------------------------------------------------
#define BAR __builtin_amdgcn_s_barrier()
#define VM0 asm volatile("s_waitcnt vmcnt(0)" ::: "memory")

#define GLDS(src, dst) \
  __builtin_amdgcn_global_load_lds( \
      (const __attribute__((address_space(1))) void*)(src), \
      (__attribute__((address_space(3))) void*)(dst), 16, 0, 0)

#define STAGE_ALL(buf) do { \
  GLDS(pA0, &As[buf][0][wid * 512]); \
  GLDS(pA1, &As[buf][0][4096 + wid * 512]); \
  GLDS(pA2, &As[buf][1][wid * 512]); \
  GLDS(pA3, &As[buf][1][4096 + wid * 512]); \
  GLDS(pB0, &Bs[buf][0][wid * 512]); \
  GLDS(pB1, &Bs[buf][0][4096 + wid * 512]); \
  GLDS(pB2, &Bs[buf][1][wid * 512]); \
  GLDS(pB3, &Bs[buf][1][4096 + wid * 512]); \
  pA0 += 64; pA1 += 64; pA2 += 64; pA3 += 64; \
  pB0 += 64; pB1 += 64; pB2 += 64; pB3 += 64; \
} while (0)

#define REGION(buf) do { \
  bf16x8 af[4][2], blo[2][2], bhi[2][2]; \
  _Pragma("unroll") \
  for (int mt = 0; mt < 4; ++mt) { \
    af[mt][0] = *(const bf16x8*)&asW[(buf) * 16384 + mt * 1024 + aO0]; \
    af[mt][1] = *(const bf16x8*)&asW[(buf) * 16384 + mt * 1024 + aO1]; \
  } \
  _Pragma("unroll") \
  for (int nt = 0; nt < 2; ++nt) { \
    blo[nt][0] = *(const bf16x8*)&bsW[(buf) * 16384 + nt * 1024 + bO0]; \
    blo[nt][1] = *(const bf16x8*)&bsW[(buf) * 16384 + nt * 1024 + bO1]; \
    bhi[nt][0] = *(const bf16x8*)&bsW[(buf) * 16384 + (2 + nt) * 1024 + bO0]; \
    bhi[nt][1] = *(const bf16x8*)&bsW[(buf) * 16384 + (2 + nt) * 1024 + bO1]; \
  } \
  __builtin_amdgcn_s_setprio(1); \
  _Pragma("unroll") \
  for (int mt = 0; mt < 4; ++mt) \
    _Pragma("unroll") \
    for (int nt = 0; nt < 2; ++nt) \
      _Pragma("unroll") \
      for (int kk = 0; kk < 2; ++kk) { \
        acc[mt][nt] = __builtin_amdgcn_mfma_f32_16x16x32_bf16( \
            af[mt][kk], blo[nt][kk], acc[mt][nt], 0, 0, 0); \
        acc[mt][2 + nt] = __builtin_amdgcn_mfma_f32_16x16x32_bf16( \
            af[mt][kk], bhi[nt][kk], acc[mt][2 + nt], 0, 0, 0); \
      } \
  __builtin_amdgcn_s_setprio(0); \
  __builtin_amdgcn_sched_barrier(0); \
  _Pragma("unroll") \
  for (int mt = 0; mt < 4; ++mt) { \
    af[mt][0] = *(const bf16x8*)&asW[(buf) * 16384 + (4 + mt) * 1024 + aO0]; \
    af[mt][1] = *(const bf16x8*)&asW[(buf) * 16384 + (4 + mt) * 1024 + aO1]; \
  } \
  __builtin_amdgcn_s_setprio(1); \
  _Pragma("unroll") \
  for (int mt = 0; mt < 4; ++mt) \
    _Pragma("unroll") \
    for (int nt = 0; nt < 2; ++nt) \
      _Pragma("unroll") \
      for (int kk = 0; kk < 2; ++kk) { \
        acc[4 + mt][2 + nt] = __builtin_amdgcn_mfma_f32_16x16x32_bf16( \
            af[mt][kk], bhi[nt][kk], acc[4 + mt][2 + nt], 0, 0, 0); \
        acc[4 + mt][nt] = __builtin_amdgcn_mfma_f32_16x16x32_bf16( \
            af[mt][kk], blo[nt][kk], acc[4 + mt][nt], 0, 0, 0); \
      } \
  __builtin_amdgcn_s_setprio(0); \
  VM0; \
  BAR; \
} while (0)

__global__ __launch_bounds__(512, 2) void gemm_kernel(
    const unsigned short* __restrict__ Abf, const unsigned short* __restrict__ w2bf,
    float* __restrict__ out, int m_base) {
  __shared__ __align__(16) unsigned short As[2][2][128 * 64];
  __shared__ __align__(16) unsigned short Bs[2][2][128 * 64];

  const int tid = threadIdx.x;
  const int lane = tid & 63;
  const int wid = tid >> 6;
  const int wr = wid >> 2;  // m-half of block
  const int wc = wid & 3;   // n-quarter of block

  // T1: bijective XCD-chunked swizzle (m204); nb fastest within chunk so the
  // 4 blocks sharing an A-panel land on the same XCD (A L2-resident).
  const int nwg = gridDim.x;
  const int bid = blockIdx.x;
  const int qq = nwg >> 3, rr = nwg & 7;
  const int xcd = bid & 7, sub = bid >> 3;
  const int wgid =
      (xcd < rr ? xcd * (qq + 1) : rr * (qq + 1) + (xcd - rr) * qq) + sub;
  const int mb = wgid >> 2;
  const int nb = wgid & 3;

  const unsigned short* Ag = Abf + (size_t)mb * 256 * F_DIM;
  const unsigned short* Bg = w2bf + (size_t)nb * 256 * F_DIM;

  f32x4 acc[8][4] = {};

  // --- LDS read bases (fold to ds_read offset immediates) ---
  const int hi4 = lane >> 4, l7 = lane & 7, l15 = lane & 15;
  const int aO0 = l15 * 64 + ((hi4 ^ l7) << 3);
  const int aO1 = aO0 ^ 32;  // kk=1: chunk XOR 4
  const int bO0 = ((wc & 1) * 64 + l15) * 64 + ((hi4 ^ l7) << 3);
  const int bO1 = bO0 ^ 32;
  const unsigned short* asW = &As[0][wr][0];
  const unsigned short* bsW = &Bs[0][wc >> 1][0];

  // --- persistent global stage pointers (advance +64 elems per K-tile) ---
  const int srow = tid >> 3;              // 0..63
  const int sc = (tid & 7) ^ (srow & 7);  // source-side swizzle
  const unsigned short* pA0 = Ag + (size_t)(srow)*F_DIM + sc * 8;
  const unsigned short* pA1 = Ag + (size_t)(64 + srow) * F_DIM + sc * 8;
  const unsigned short* pA2 = Ag + (size_t)(128 + srow) * F_DIM + sc * 8;
  const unsigned short* pA3 = Ag + (size_t)(192 + srow) * F_DIM + sc * 8;
  const unsigned short* pB0 = Bg + (size_t)(srow)*F_DIM + sc * 8;
  const unsigned short* pB1 = Bg + (size_t)(64 + srow) * F_DIM + sc * 8;
  const unsigned short* pB2 = Bg + (size_t)(128 + srow) * F_DIM + sc * 8;
  const unsigned short* pB3 = Bg + (size_t)(192 + srow) * F_DIM + sc * 8;

  // --- prologue: stage kt0 -> buf0 ---
  STAGE_ALL(0);
  VM0;
  BAR;

#pragma unroll 1
  for (int t2 = 0; t2 < 32; ++t2) {
    // ---- kt = 2*t2 (buf0); stage kt+1 -> buf1 ----
    STAGE_ALL(1);
    REGION(0);
    // ---- kt = 2*t2+1 (buf1); stage kt+2 -> buf0 ----
    if (t2 < 31) STAGE_ALL(0);
    REGION(1);
  }

  // Epilogue: C/D layout col = lane&15, row = (lane>>4)*4 + r [m89-verified]
  const int cl = lane & 15, rg = lane >> 4;
  float* ob = out + (size_t)(m_base + mb * 256 + wr * 128) * E_DIM + nb * 256 +
              wc * 64 + cl;
#pragma unroll
  for (int mt = 0; mt < 8; ++mt)
#pragma unroll
    for (int r = 0; r < 4; ++r) {
      float* orow = ob + (size_t)(mt * 16 + rg * 4 + r) * E_DIM;
#pragma unroll
      for (int nt = 0; nt < 4; ++nt) orow[nt * 16] = acc[mt][nt][r];
    }
}

// ---------------------------------------------------------------------------
extern "C" void kernel_launch(void* const* d_in, const int* in_sizes, int n_in,
                              void* d_out, int out_size, void* d_ws, size_t ws_size,
                              hipStream_t stream) {
  const float* x = (const float*)d_in[0];
  const float* theta = (const float*)d_in[1];
  const float* w1 = (const float*)d_in[2];
  const float* w2 = (const float*)d_in[3];
  float* out = (float*)d_out;

  unsigned short* w2bf = (unsigned short*)d_ws;           // 8 MiB
  unsigned short* A = w2bf + (size_t)E_DIM * F_DIM;       // rest of ws

  size_t abytes = ws_size - (size_t)E_DIM * F_DIM * 2;
  size_t maxrows = abytes / ((size_t)F_DIM * 2);
  int Mc = (int)((maxrows / 256) * 256);
  if (Mc > M_TOTAL) Mc = M_TOTAL;
  if (Mc < 256) Mc = 256;

  w2cvt_kernel<<<E_DIM * F_DIM / 2048, 256, 0, stream>>>(w2, w2bf);

  for (int mb = 0; mb < M_TOTAL; mb += Mc) {
    int rows = M_TOTAL - mb < Mc ? M_TOTAL - mb : Mc;
    qrelu_kernel<<<rows / 32, 256, 0, stream>>>(x, theta, w1, A, mb);
    gemm_kernel<<<(rows / 256) * 4, 512, 0, stream>>>(A, w2bf, out, mb);
  }
}

// Round 8
// 156.262 us; speedup vs baseline: 1.4197x; 1.0027x over previous
//
#include <hip/hip_runtime.h>
#include <hip/hip_bf16.h>

// out[m,e] = sum_f relu( sum_q cos(x[m,q])cos(theta[q]) w1[f,q] ) * w2[e,f]
// M=16384, E=1024, F=4096. Pipeline:
//   1) w2cvt: w2 fp32 -> bf16 once into ws
//   2) qrelu: A = relu(qv @ w1^T) bf16 into ws
//   3) gemm: out = A @ w2bf^T -- 256x256 tile, BK=64, 8 waves (2m x 4n).
//      ONE region per K-tile, fine-grained {1 ds_read, 4 MFMA} round-robin
//      (DS pipe drains under the MFMA clusters; 2-step read-ahead window
//      keeps frag liveness ~28 VGPR -> no spill), vmcnt(0) gate before the
//      single barrier. LDS XOR-swizzle, XCD swizzle, setprio.

#define M_TOTAL 16384
#define E_DIM 1024
#define F_DIM 4096
#define NQ 8

typedef __attribute__((ext_vector_type(8))) short bf16x8;
typedef __attribute__((ext_vector_type(8))) unsigned short ushort8;
typedef __attribute__((ext_vector_type(4))) float f32x4;

__device__ __forceinline__ unsigned short f2bf(float f) {
  union { float f; unsigned u; } c; c.f = f;
  unsigned u = c.u + (0x7fffu + ((c.u >> 16) & 1u));
  return (unsigned short)(u >> 16);
}

// ---------------------------------------------------------------------------
__global__ __launch_bounds__(256) void w2cvt_kernel(
    const float* __restrict__ w2, unsigned short* __restrict__ w2bf) {
  size_t i = ((size_t)blockIdx.x * 256 + threadIdx.x) * 8;
  float v[8];
  *(float4*)&v[0] = *(const float4*)&w2[i];
  *(float4*)&v[4] = *(const float4*)&w2[i + 4];
  ushort8 p;
#pragma unroll
  for (int j = 0; j < 8; ++j) p[j] = f2bf(v[j]);
  *(ushort8*)&w2bf[i] = p;
}

// ---------------------------------------------------------------------------
__global__ __launch_bounds__(256) void qrelu_kernel(
    const float* __restrict__ x, const float* __restrict__ theta,
    const float* __restrict__ w1, unsigned short* __restrict__ A, int m_base) {
  __shared__ float qv[32][NQ];
  const int t = threadIdx.x;
  const int m0 = m_base + blockIdx.x * 32;
  {
    const int ml = t >> 3, q = t & 7;
    float xv = x[(size_t)(m0 + ml) * 1024 + q];
    qv[ml][q] = cosf(xv) * cosf(theta[q]);
  }
  __syncthreads();

  for (int oi = 0; oi < 2; ++oi) {
    const int o = t + oi * 256;  // f-octet index 0..511
    float w[64];
#pragma unroll
    for (int i = 0; i < 16; ++i)
      *(float4*)&w[i * 4] = *(const float4*)&w1[o * 64 + i * 4];
    for (int ml = 0; ml < 32; ++ml) {
      ushort8 pk;
#pragma unroll
      for (int j = 0; j < 8; ++j) {
        float s = 0.f;
#pragma unroll
        for (int q = 0; q < NQ; ++q) s = fmaf(qv[ml][q], w[j * 8 + q], s);
        pk[j] = f2bf(s > 0.f ? s : 0.f);
      }
      *(ushort8*)&A[(size_t)(m0 - m_base + ml) * F_DIM + o * 8] = pk;
    }
  }
}

// ---------------------------------------------------------------------------
// GEMM: BM=BN=256, BK=64, 512 thr = 8 waves (2m x 4n), wave tile 128x64.
// LDS: As/Bs [2 buf][2 half][128*64] bf16 = 128 KiB. Swizzle: (row, chunk c)
// stored at chunk c ^ (row&7); pre-swizzled global source, XOR'd ds_read.
// Region(kt), buf = kt&1, split into kk-halves; per half:
//   pre-read bf[0..3][kk] + af[0..1][kk]   (6 ds_read)
//   step mt=0..7: { read af[mt+2][kk] (mt<6); setprio(1); 4 MFMA (mt x nt);
//                   setprio(0); sched_barrier(0) }
// Reads stay 2 steps (~310 MFMA-cyc) ahead of use; DS pipe drains UNDER the
// MFMA clusters; per-step sched_barrier stops read-hoisting (r6's spill).
// All lgkm waits remain compiler-counted (never forced to 0 mid-region).
// [vmcnt(0)] [s_barrier] once per K-tile gates the staged buffer (RAW) and
// buffer reuse (WAR: every ds_read has a consuming MFMA before the barrier).
// ---------------------------------------------------------------------------
#define BAR __builtin_amdgcn_s_barrier()
#define VM0 asm volatile("s_waitcnt vmcnt(0)" ::: "memory")

#define GLDS(src, dst) \
  __builtin_amdgcn_global_load_lds( \
      (const __attribute__((address_space(1))) void*)(src), \
      (__attribute__((address_space(3))) void*)(dst), 16, 0, 0)

#define STAGE_ALL(buf) do { \
  GLDS(pA0, &As[buf][0][wid * 512]); \
  GLDS(pA1, &As[buf][0][4096 + wid * 512]); \
  GLDS(pA2, &As[buf][1][wid * 512]); \
  GLDS(pA3, &As[buf][1][4096 + wid * 512]); \
  GLDS(pB0, &Bs[buf][0][wid * 512]); \
  GLDS(pB1, &Bs[buf][0][4096 + wid * 512]); \
  GLDS(pB2, &Bs[buf][1][wid * 512]); \
  GLDS(pB3, &Bs[buf][1][4096 + wid * 512]); \
  pA0 += 64; pA1 += 64; pA2 += 64; pA3 += 64; \
  pB0 += 64; pB1 += 64; pB2 += 64; pB3 += 64; \
} while (0)

#define RDA(buf, mt, kk) \
  (*(const bf16x8*)&asW[(buf) * 16384 + (mt) * 1024 + ((kk) ? aO1 : aO0)])
#define RDB(buf, nt, kk) \
  (*(const bf16x8*)&bsW[(buf) * 16384 + (nt) * 1024 + ((kk) ? bO1 : bO0)])

#define STEP(buf, kk, mt) do { \
  if ((mt) < 6) af3[((mt) + 2) % 3] = RDA(buf, (mt) + 2, kk); \
  __builtin_amdgcn_s_setprio(1); \
  acc[mt][0] = __builtin_amdgcn_mfma_f32_16x16x32_bf16( \
      af3[(mt) % 3], bf4[0], acc[mt][0], 0, 0, 0); \
  acc[mt][1] = __builtin_amdgcn_mfma_f32_16x16x32_bf16( \
      af3[(mt) % 3], bf4[1], acc[mt][1], 0, 0, 0); \
  acc[mt][2] = __builtin_amdgcn_mfma_f32_16x16x32_bf16( \
      af3[(mt) % 3], bf4[2], acc[mt][2], 0, 0, 0); \
  acc[mt][3] = __builtin_amdgcn_mfma_f32_16x16x32_bf16( \
      af3[(mt) % 3], bf4[3], acc[mt][3], 0, 0, 0); \
  __builtin_amdgcn_s_setprio(0); \
  __builtin_amdgcn_sched_barrier(0); \
} while (0)

#define HALF(buf, kk) do { \
  bf16x8 af3[3], bf4[4]; \
  bf4[0] = RDB(buf, 0, kk); \
  bf4[1] = RDB(buf, 1, kk); \
  bf4[2] = RDB(buf, 2, kk); \
  bf4[3] = RDB(buf, 3, kk); \
  af3[0] = RDA(buf, 0, kk); \
  af3[1] = RDA(buf, 1, kk); \
  STEP(buf, kk, 0); STEP(buf, kk, 1); STEP(buf, kk, 2); STEP(buf, kk, 3); \
  STEP(buf, kk, 4); STEP(buf, kk, 5); STEP(buf, kk, 6); STEP(buf, kk, 7); \
} while (0)

#define REGION(buf) do { \
  HALF(buf, 0); \
  HALF(buf, 1); \
  VM0; \
  BAR; \
} while (0)

__global__ __launch_bounds__(512, 2) void gemm_kernel(
    const unsigned short* __restrict__ Abf, const unsigned short* __restrict__ w2bf,
    float* __restrict__ out, int m_base) {
  __shared__ __align__(16) unsigned short As[2][2][128 * 64];
  __shared__ __align__(16) unsigned short Bs[2][2][128 * 64];

  const int tid = threadIdx.x;
  const int lane = tid & 63;
  const int wid = tid >> 6;
  const int wr = wid >> 2;  // m-half of block
  const int wc = wid & 3;   // n-quarter of block

  // T1: bijective XCD-chunked swizzle (m204); nb fastest within chunk so the
  // 4 blocks sharing an A-panel land on the same XCD (A L2-resident).
  const int nwg = gridDim.x;
  const int bid = blockIdx.x;
  const int qq = nwg >> 3, rr = nwg & 7;
  const int xcd = bid & 7, sub = bid >> 3;
  const int wgid =
      (xcd < rr ? xcd * (qq + 1) : rr * (qq + 1) + (xcd - rr) * qq) + sub;
  const int mb = wgid >> 2;
  const int nb = wgid & 3;

  const unsigned short* Ag = Abf + (size_t)mb * 256 * F_DIM;
  const unsigned short* Bg = w2bf + (size_t)nb * 256 * F_DIM;

  f32x4 acc[8][4] = {};

  // --- LDS read bases (fold to ds_read offset immediates) ---
  const int hi4 = lane >> 4, l7 = lane & 7, l15 = lane & 15;
  const int aO0 = l15 * 64 + ((hi4 ^ l7) << 3);
  const int aO1 = aO0 ^ 32;  // kk=1: chunk XOR 4
  const int bO0 = ((wc & 1) * 64 + l15) * 64 + ((hi4 ^ l7) << 3);
  const int bO1 = bO0 ^ 32;
  const unsigned short* asW = &As[0][wr][0];
  const unsigned short* bsW = &Bs[0][wc >> 1][0];

  // --- persistent global stage pointers (advance +64 elems per K-tile) ---
  const int srow = tid >> 3;              // 0..63
  const int sc = (tid & 7) ^ (srow & 7);  // source-side swizzle
  const unsigned short* pA0 = Ag + (size_t)(srow)*F_DIM + sc * 8;
  const unsigned short* pA1 = Ag + (size_t)(64 + srow) * F_DIM + sc * 8;
  const unsigned short* pA2 = Ag + (size_t)(128 + srow) * F_DIM + sc * 8;
  const unsigned short* pA3 = Ag + (size_t)(192 + srow) * F_DIM + sc * 8;
  const unsigned short* pB0 = Bg + (size_t)(srow)*F_DIM + sc * 8;
  const unsigned short* pB1 = Bg + (size_t)(64 + srow) * F_DIM + sc * 8;
  const unsigned short* pB2 = Bg + (size_t)(128 + srow) * F_DIM + sc * 8;
  const unsigned short* pB3 = Bg + (size_t)(192 + srow) * F_DIM + sc * 8;

  // --- prologue: stage kt0 -> buf0 ---
  STAGE_ALL(0);
  VM0;
  BAR;

#pragma unroll 1
  for (int t2 = 0; t2 < 32; ++t2) {
    // ---- kt = 2*t2 (buf0); stage kt+1 -> buf1 ----
    STAGE_ALL(1);
    REGION(0);
    // ---- kt = 2*t2+1 (buf1); stage kt+2 -> buf0 ----
    if (t2 < 31) STAGE_ALL(0);
    REGION(1);
  }

  // Epilogue: C/D layout col = lane&15, row = (lane>>4)*4 + r [m89-verified]
  const int cl = lane & 15, rg = lane >> 4;
  float* ob = out + (size_t)(m_base + mb * 256 + wr * 128) * E_DIM + nb * 256 +
              wc * 64 + cl;
#pragma unroll
  for (int mt = 0; mt < 8; ++mt)
#pragma unroll
    for (int r = 0; r < 4; ++r) {
      float* orow = ob + (size_t)(mt * 16 + rg * 4 + r) * E_DIM;
#pragma unroll
      for (int nt = 0; nt < 4; ++nt) orow[nt * 16] = acc[mt][nt][r];
    }
}

// ---------------------------------------------------------------------------
extern "C" void kernel_launch(void* const* d_in, const int* in_sizes, int n_in,
                              void* d_out, int out_size, void* d_ws, size_t ws_size,
                              hipStream_t stream) {
  const float* x = (const float*)d_in[0];
  const float* theta = (const float*)d_in[1];
  const float* w1 = (const float*)d_in[2];
  const float* w2 = (const float*)d_in[3];
  float* out = (float*)d_out;

  unsigned short* w2bf = (unsigned short*)d_ws;           // 8 MiB
  unsigned short* A = w2bf + (size_t)E_DIM * F_DIM;       // rest of ws

  size_t abytes = ws_size - (size_t)E_DIM * F_DIM * 2;
  size_t maxrows = abytes / ((size_t)F_DIM * 2);
  int Mc = (int)((maxrows / 256) * 256);
  if (Mc > M_TOTAL) Mc = M_TOTAL;
  if (Mc < 256) Mc = 256;

  w2cvt_kernel<<<E_DIM * F_DIM / 2048, 256, 0, stream>>>(w2, w2bf);

  for (int mb = 0; mb < M_TOTAL; mb += Mc) {
    int rows = M_TOTAL - mb < Mc ? M_TOTAL - mb : Mc;
    qrelu_kernel<<<rows / 32, 256, 0, stream>>>(x, theta, w1, A, mb);
    gemm_kernel<<<(rows / 256) * 4, 512, 0, stream>>>(A, w2bf, out, mb);
  }
}